// Round 3
// baseline (202.727 us; speedup 1.0000x reference)
//
#include <hip/hip_runtime.h>
#include <hip/hip_bf16.h>
#include <math.h>

#define B_    64
#define TQ    32
#define TD    4096
#define HDIM  300
#define NB    29      // histogram bins
#define NFEAT 30      // 29 bins + exact-match feature
#define DTILE 256
#define NCHUNK 16     // TD / DTILE
#define HC    60      // h chunk size
#define NHC   5       // HDIM / HC
#define THREADS 512

// bin upper bounds: jnp.linspace(-1,1,30)[1:], ub[k] = -1 + 2(k+1)/29
__device__ __forceinline__ float ubf(int k) {
    return (float)(-1.0 + (2.0 * (double)(k + 1)) / 29.0);
}

// bin one similarity value into the per-block LDS histogram
__device__ __forceinline__ void bin_one(float sim, unsigned* s_hist, int q) {
    if (sim > 0.999f && sim < 1.001f) {
        // only exact token matches land here; true sim < 1.0 strictly -> bin 28
        atomicAdd(&s_hist[q * NFEAT + 28], 1u);
        atomicAdd(&s_hist[q * NFEAT + 29], 1u);   // exact-match feature
    } else {
        int idx = (int)((sim + 1.0f) * 14.5f);    // guess, then exact fixup
        idx = idx < 0 ? 0 : (idx > NB ? NB : idx);
        while (idx < NB && sim >= ubf(idx)) ++idx;
        while (idx > 0 && sim < ubf(idx - 1)) --idx;
        if (idx < NB) atomicAdd(&s_hist[q * NFEAT + idx], 1u);
    }
}

// ---------------- main: fused norms + sim GEMM + histogram ----------------
// 512 threads = 8 waves; tile 32q x 256d.
// Wave w: q rows (w&3)*8..+7, d half (w>>2): lane owns d = half*128 + lane*2 (+0,+1).
// Staging: thread t stages d-row (t&255), h-half (t>>8); threads<64 also stage q rows.
// d-rows for chunk hc+1 are prefetched into registers before computing chunk hc (T14).
__global__ __launch_bounds__(THREADS, 4) void k_main(
        const int* __restrict__ sent, const int* __restrict__ qsent,
        const float* __restrict__ emb, unsigned* __restrict__ ghist) {
    __shared__ __align__(16) float dxT[HC][DTILE];   // 61.4 KB transposed tile
    __shared__ __align__(16) float qxT[HC][TQ];      // 7.7 KB
    __shared__ int      toks[DTILE];
    __shared__ int      qtk[TQ];
    __shared__ float    s_iq[TQ];
    __shared__ float    s_id[DTILE];
    __shared__ unsigned s_hist[TQ * NFEAT];
    __shared__ float    pnd[2][DTILE];               // norm partials
    __shared__ float    pnq[2][TQ];

    const int b    = blockIdx.x >> 4;
    const int d0   = (blockIdx.x & 15) * DTILE;
    const int tid  = threadIdx.x;
    const int wid  = tid >> 6;
    const int lane = tid & 63;

    if (tid < DTILE) toks[tid] = sent[b * TD + d0 + tid];
    if (tid < TQ)    qtk[tid]  = qsent[b * TQ + tid];
    __syncthreads();

    // staging roles (uniform per wave: dhalf = tid>>8)
    const int drow  = tid & 255;
    const int dhalf = tid >> 8;              // 0: h 0..31 of chunk, 1: h 32..59
    const int nfd   = 8 - dhalf;             // 8 or 7 float4 per chunk
    const int hofs  = dhalf * 32;
    const float* dptr0 = emb + (size_t)toks[drow] * HDIM + hofs;
    const bool  doq   = (tid < 64);
    const int   qrow  = tid & 31;
    const int   qhalf = (tid >> 5) & 1;
    const int   nfq   = 8 - qhalf;
    const int   qhofs = qhalf * 32;
    const float* qptr0 = doq ? (emb + (size_t)qtk[qrow] * HDIM + qhofs) : emb;

    float nd = 0.f, nq = 0.f;                // per-thread norm partials

    // compute roles
    const int q0  = (wid & 3) * 8;
    const int myd = ((wid >> 2) << 7) + lane * 2;

    float acc[8][2];
#pragma unroll
    for (int qi = 0; qi < 8; ++qi) { acc[qi][0] = 0.f; acc[qi][1] = 0.f; }

    // ---- prefetch chunk 0 d-rows into registers
    float4 dreg[8];
#pragma unroll
    for (int jf = 0; jf < 8; ++jf)
        if (jf < nfd) dreg[jf] = *(const float4*)(dptr0 + jf * 4);

    for (int hc = 0; hc < NHC; ++hc) {
        const int hb = hc * HC;

        // ---- issue q loads first (latency hides under d writes below)
        float4 qv[8];
        if (doq) {
#pragma unroll
            for (int jf = 0; jf < 8; ++jf)
                if (jf < nfq) qv[jf] = *(const float4*)(qptr0 + hb + jf * 4);
        }

        // ---- write prefetched d-rows: column writes, lanes = consecutive rows
#pragma unroll
        for (int jf = 0; jf < 8; ++jf) {
            if (jf < nfd) {
                float4 v = dreg[jf];
                int h = hofs + jf * 4;
                dxT[h + 0][drow] = v.x; dxT[h + 1][drow] = v.y;
                dxT[h + 2][drow] = v.z; dxT[h + 3][drow] = v.w;
                nd = fmaf(v.x, v.x, nd); nd = fmaf(v.y, v.y, nd);
                nd = fmaf(v.z, v.z, nd); nd = fmaf(v.w, v.w, nd);
            }
        }
        // ---- write q rows
        if (doq) {
#pragma unroll
            for (int jf = 0; jf < 8; ++jf) {
                if (jf < nfq) {
                    float4 v = qv[jf];
                    int h = qhofs + jf * 4;
                    qxT[h + 0][qrow] = v.x; qxT[h + 1][qrow] = v.y;
                    qxT[h + 2][qrow] = v.z; qxT[h + 3][qrow] = v.w;
                    nq = fmaf(v.x, v.x, nq); nq = fmaf(v.y, v.y, nq);
                    nq = fmaf(v.z, v.z, nq); nq = fmaf(v.w, v.w, nq);
                }
            }
        }
        // ---- prefetch next chunk's d-rows (in flight across the compute phase)
        if (hc + 1 < NHC) {
            const float* p = dptr0 + hb + HC;
#pragma unroll
            for (int jf = 0; jf < 8; ++jf)
                if (jf < nfd) dreg[jf] = *(const float4*)(p + jf * 4);
        }
        __syncthreads();

        // ---- compute: per h: 1 lane-contiguous float2 (dx) + 2 uniform float4 (qx), 16 FMA
#pragma unroll 3
        for (int h4 = 0; h4 < 15; ++h4) {
#pragma unroll
            for (int j = 0; j < 4; ++j) {
                const int h = h4 * 4 + j;
                float2 dv = *(const float2*)&dxT[h][myd];
                float4 a  = *(const float4*)&qxT[h][q0];
                float4 c  = *(const float4*)&qxT[h][q0 + 4];
                acc[0][0] = fmaf(a.x, dv.x, acc[0][0]); acc[0][1] = fmaf(a.x, dv.y, acc[0][1]);
                acc[1][0] = fmaf(a.y, dv.x, acc[1][0]); acc[1][1] = fmaf(a.y, dv.y, acc[1][1]);
                acc[2][0] = fmaf(a.z, dv.x, acc[2][0]); acc[2][1] = fmaf(a.z, dv.y, acc[2][1]);
                acc[3][0] = fmaf(a.w, dv.x, acc[3][0]); acc[3][1] = fmaf(a.w, dv.y, acc[3][1]);
                acc[4][0] = fmaf(c.x, dv.x, acc[4][0]); acc[4][1] = fmaf(c.x, dv.y, acc[4][1]);
                acc[5][0] = fmaf(c.y, dv.x, acc[5][0]); acc[5][1] = fmaf(c.y, dv.y, acc[5][1]);
                acc[6][0] = fmaf(c.z, dv.x, acc[6][0]); acc[6][1] = fmaf(c.z, dv.y, acc[6][1]);
                acc[7][0] = fmaf(c.w, dv.x, acc[7][0]); acc[7][1] = fmaf(c.w, dv.y, acc[7][1]);
            }
        }
        __syncthreads();   // before next chunk overwrites dxT/qxT
    }

    // ---- finalize norms (deterministic 2-partial sum), init hist
    pnd[dhalf][drow] = nd;
    if (doq) pnq[qhalf][qrow] = nq;
    __syncthreads();
    if (tid < DTILE) {
        float s = pnd[0][tid] + pnd[1][tid];
        s_id[tid] = 1.0f / (sqrtf(s + 1e-7f) + 1e-7f);
    } else if (tid < DTILE + TQ) {
        int q = tid - DTILE;
        float s = pnq[0][q] + pnq[1][q];
        s_iq[q] = 1.0f / (sqrtf(s + 1e-7f) + 1e-7f);
    }
    for (int i = tid; i < TQ * NFEAT; i += THREADS) s_hist[i] = 0u;
    __syncthreads();

    // ---- epilogue: sim -> bins (FULLY unrolled: acc must stay in registers)
    {
        const float id0 = s_id[myd];
        const float id1 = s_id[myd + 1];
        const bool  v0  = (toks[myd] != 0);
        const bool  v1  = (toks[myd + 1] != 0);
#pragma unroll
        for (int qi = 0; qi < 8; ++qi) {
            const int q = q0 + qi;
            const float iq = s_iq[q];
            if (v0) bin_one(acc[qi][0] * iq * id0, s_hist, q);
            if (v1) bin_one(acc[qi][1] * iq * id1, s_hist, q);
        }
    }
    __syncthreads();
    for (int i = tid; i < TQ * NFEAT; i += THREADS) {
        unsigned v = s_hist[i];
        if (v) atomicAdd(&ghist[b * TQ * NFEAT + i], v);
    }
}

// ---------------- finish: log + MLP + gate softmax ----------------
__global__ void k_finish(const unsigned* __restrict__ ghist,
                         const int* __restrict__ qsent, const float* __restrict__ idf,
                         const float* __restrict__ w1, const float* __restrict__ b1,
                         const float* __restrict__ w2, const float* __restrict__ b2,
                         const float* __restrict__ gw, const float* __restrict__ ow,
                         const float* __restrict__ ob, float* __restrict__ out) {
    int b = blockIdx.x;
    int lane = threadIdx.x;   // 64 threads, lanes 0..31 active
    float ffw = 0.f;
    float logit = -3.0e38f;
    if (lane < TQ) {
        const unsigned* h = ghist + (b * TQ + lane) * NFEAT;
        float f[NFEAT];
        for (int k = 0; k < NFEAT; ++k) f[k] = logf((float)h[k] + 1.0f);
        float s2 = b2[0];
        for (int n = 0; n < 5; ++n) {
            float s = b1[n];
            for (int k = 0; k < NFEAT; ++k) s = fmaf(f[k], w1[k * 5 + n], s);
            s2 = fmaf(tanhf(s), w2[n], s2);
        }
        ffw = tanhf(s2);
        int qt = qsent[b * TQ + lane];
        logit = idf[b * TQ + lane] * gw[0] + (qt == 0 ? -1e7f : 0.f);
    }
    float m = logit;
#pragma unroll
    for (int t = 1; t < 64; t <<= 1) m = fmaxf(m, __shfl_xor(m, t, 64));
    float e = expf(logit - m);            // inactive lanes -> exp(-inf) = 0
    float se = e, sw = e * ffw;
#pragma unroll
    for (int t = 1; t < 64; t <<= 1) {
        se += __shfl_xor(se, t, 64);
        sw += __shfl_xor(sw, t, 64);
    }
    if (lane == 0) out[b] = (sw / se) * ow[0] + ob[0];
}

extern "C" void kernel_launch(void* const* d_in, const int* in_sizes, int n_in,
                              void* d_out, int out_size, void* d_ws, size_t ws_size,
                              hipStream_t stream) {
    const int*   sent  = (const int*)d_in[0];
    const int*   qsent = (const int*)d_in[1];
    const float* idf   = (const float*)d_in[2];
    const float* emb   = (const float*)d_in[3];
    const float* w1    = (const float*)d_in[4];
    const float* b1    = (const float*)d_in[5];
    const float* w2    = (const float*)d_in[6];
    const float* b2    = (const float*)d_in[7];
    const float* gw    = (const float*)d_in[8];
    const float* ow    = (const float*)d_in[9];
    const float* ob    = (const float*)d_in[10];
    float* out = (float*)d_out;

    unsigned* ghist = (unsigned*)d_ws;                 // 64*32*30 u32 = 240 KB

    hipMemsetAsync(ghist, 0, (size_t)B_ * TQ * NFEAT * 4, stream);
    k_main<<<B_ * NCHUNK, THREADS, 0, stream>>>(sent, qsent, emb, ghist);
    k_finish<<<B_, 64, 0, stream>>>(ghist, qsent, idf, w1, b1, w2, b2, gw, ow, ob, out);
}

// Round 4
// 192.809 us; speedup vs baseline: 1.0514x; 1.0514x over previous
//
#include <hip/hip_runtime.h>
#include <hip/hip_bf16.h>
#include <math.h>

#define B_    64
#define TQ    32
#define TD    4096
#define HDIM  300
#define NB    29      // histogram bins
#define NFEAT 30      // 29 bins + exact-match feature
#define DTILE 256
#define NCHUNK 16     // TD / DTILE
#define HC    60      // h chunk size
#define NHC   5       // HDIM / HC
#define THREADS 512

// bin upper bounds: jnp.linspace(-1,1,30)[1:], ub[k] = -1 + 2(k+1)/29
__device__ __forceinline__ float ubf(int k) {
    return (float)(-1.0 + (2.0 * (double)(k + 1)) / 29.0);
}

// bin one similarity value into the per-block LDS histogram
__device__ __forceinline__ void bin_one(float sim, unsigned* s_hist, int q) {
    if (sim > 0.999f && sim < 1.001f) {
        // only exact token matches land here; true sim < 1.0 strictly -> bin 28
        atomicAdd(&s_hist[q * NFEAT + 28], 1u);
        atomicAdd(&s_hist[q * NFEAT + 29], 1u);   // exact-match feature
    } else {
        int idx = (int)((sim + 1.0f) * 14.5f);    // guess, then exact fixup
        idx = idx < 0 ? 0 : (idx > NB ? NB : idx);
        while (idx < NB && sim >= ubf(idx)) ++idx;
        while (idx > 0 && sim < ubf(idx - 1)) --idx;
        if (idx < NB) atomicAdd(&s_hist[q * NFEAT + idx], 1u);
    }
}

// ---------------- main: fused norms + sim GEMM + histogram ----------------
// 512 threads = 8 waves; tile 32q x 256d.
// Wave w: q rows (w&3)*8..+7, d half (w>>2): lane owns d = half*128 + lane*2 (+0,+1).
// Staging: thread t stages d-row (t&255), h-half (t>>8); threads<64 also stage q rows.
// d-rows for chunk hc+1 are prefetched into registers before computing chunk hc (T14).
// NOTE: launch_bounds 2nd arg behaves as min-BLOCKS/CU on this hipcc: (512,4) capped
// VGPR at 64 and spilled the prefetch regs (r3: WRITE_SIZE 143MB of scratch). LDS
// (77.8KB) caps occupancy at 2 blocks/CU anyway, so request exactly 2 -> 128-VGPR cap.
__global__ __launch_bounds__(THREADS, 2) void k_main(
        const int* __restrict__ sent, const int* __restrict__ qsent,
        const float* __restrict__ emb, unsigned* __restrict__ ghist) {
    __shared__ __align__(16) float dxT[HC][DTILE];   // 61.4 KB transposed tile
    __shared__ __align__(16) float qxT[HC][TQ];      // 7.7 KB
    __shared__ int      toks[DTILE];
    __shared__ int      qtk[TQ];
    __shared__ float    s_iq[TQ];
    __shared__ float    s_id[DTILE];
    __shared__ unsigned s_hist[TQ * NFEAT];
    __shared__ float    pnd[2][DTILE];               // norm partials
    __shared__ float    pnq[2][TQ];

    const int b    = blockIdx.x >> 4;
    const int d0   = (blockIdx.x & 15) * DTILE;
    const int tid  = threadIdx.x;
    const int wid  = tid >> 6;
    const int lane = tid & 63;

    if (tid < DTILE) toks[tid] = sent[b * TD + d0 + tid];
    if (tid < TQ)    qtk[tid]  = qsent[b * TQ + tid];
    __syncthreads();

    // staging roles (uniform per wave: dhalf = tid>>8)
    const int drow  = tid & 255;
    const int dhalf = tid >> 8;              // 0: h 0..31 of chunk, 1: h 32..59
    const int nfd   = 8 - dhalf;             // 8 or 7 float4 per chunk
    const int hofs  = dhalf * 32;
    const float* dptr0 = emb + (size_t)toks[drow] * HDIM + hofs;
    const bool  doq   = (tid < 64);
    const int   qrow  = tid & 31;
    const int   qhalf = (tid >> 5) & 1;
    const int   nfq   = 8 - qhalf;
    const int   qhofs = qhalf * 32;
    const float* qptr0 = doq ? (emb + (size_t)qtk[qrow] * HDIM + qhofs) : emb;

    float nd = 0.f, nq = 0.f;                // per-thread norm partials

    // compute roles
    const int q0  = (wid & 3) * 8;
    const int myd = ((wid >> 2) << 7) + lane * 2;

    float acc[8][2];
#pragma unroll
    for (int qi = 0; qi < 8; ++qi) { acc[qi][0] = 0.f; acc[qi][1] = 0.f; }

    // ---- prefetch chunk 0 d-rows into registers
    float4 dreg[8];
#pragma unroll
    for (int jf = 0; jf < 8; ++jf)
        if (jf < nfd) dreg[jf] = *(const float4*)(dptr0 + jf * 4);

    for (int hc = 0; hc < NHC; ++hc) {
        const int hb = hc * HC;

        // ---- issue q loads first (latency hides under d writes below)
        float4 qv[8];
        if (doq) {
#pragma unroll
            for (int jf = 0; jf < 8; ++jf)
                if (jf < nfq) qv[jf] = *(const float4*)(qptr0 + hb + jf * 4);
        }

        // ---- write prefetched d-rows: column writes, lanes = consecutive rows
#pragma unroll
        for (int jf = 0; jf < 8; ++jf) {
            if (jf < nfd) {
                float4 v = dreg[jf];
                int h = hofs + jf * 4;
                dxT[h + 0][drow] = v.x; dxT[h + 1][drow] = v.y;
                dxT[h + 2][drow] = v.z; dxT[h + 3][drow] = v.w;
                nd = fmaf(v.x, v.x, nd); nd = fmaf(v.y, v.y, nd);
                nd = fmaf(v.z, v.z, nd); nd = fmaf(v.w, v.w, nd);
            }
        }
        // ---- write q rows
        if (doq) {
#pragma unroll
            for (int jf = 0; jf < 8; ++jf) {
                if (jf < nfq) {
                    float4 v = qv[jf];
                    int h = qhofs + jf * 4;
                    qxT[h + 0][qrow] = v.x; qxT[h + 1][qrow] = v.y;
                    qxT[h + 2][qrow] = v.z; qxT[h + 3][qrow] = v.w;
                    nq = fmaf(v.x, v.x, nq); nq = fmaf(v.y, v.y, nq);
                    nq = fmaf(v.z, v.z, nq); nq = fmaf(v.w, v.w, nq);
                }
            }
        }
        // ---- prefetch next chunk's d-rows (in flight across the compute phase)
        if (hc + 1 < NHC) {
            const float* p = dptr0 + hb + HC;
#pragma unroll
            for (int jf = 0; jf < 8; ++jf)
                if (jf < nfd) dreg[jf] = *(const float4*)(p + jf * 4);
        }
        __syncthreads();

        // ---- compute: per h: 1 lane-contiguous float2 (dx) + 2 uniform float4 (qx), 16 FMA
#pragma unroll 3
        for (int h4 = 0; h4 < 15; ++h4) {
#pragma unroll
            for (int j = 0; j < 4; ++j) {
                const int h = h4 * 4 + j;
                float2 dv = *(const float2*)&dxT[h][myd];
                float4 a  = *(const float4*)&qxT[h][q0];
                float4 c  = *(const float4*)&qxT[h][q0 + 4];
                acc[0][0] = fmaf(a.x, dv.x, acc[0][0]); acc[0][1] = fmaf(a.x, dv.y, acc[0][1]);
                acc[1][0] = fmaf(a.y, dv.x, acc[1][0]); acc[1][1] = fmaf(a.y, dv.y, acc[1][1]);
                acc[2][0] = fmaf(a.z, dv.x, acc[2][0]); acc[2][1] = fmaf(a.z, dv.y, acc[2][1]);
                acc[3][0] = fmaf(a.w, dv.x, acc[3][0]); acc[3][1] = fmaf(a.w, dv.y, acc[3][1]);
                acc[4][0] = fmaf(c.x, dv.x, acc[4][0]); acc[4][1] = fmaf(c.x, dv.y, acc[4][1]);
                acc[5][0] = fmaf(c.y, dv.x, acc[5][0]); acc[5][1] = fmaf(c.y, dv.y, acc[5][1]);
                acc[6][0] = fmaf(c.z, dv.x, acc[6][0]); acc[6][1] = fmaf(c.z, dv.y, acc[6][1]);
                acc[7][0] = fmaf(c.w, dv.x, acc[7][0]); acc[7][1] = fmaf(c.w, dv.y, acc[7][1]);
            }
        }
        __syncthreads();   // before next chunk overwrites dxT/qxT
    }

    // ---- finalize norms (deterministic 2-partial sum), init hist
    pnd[dhalf][drow] = nd;
    if (doq) pnq[qhalf][qrow] = nq;
    __syncthreads();
    if (tid < DTILE) {
        float s = pnd[0][tid] + pnd[1][tid];
        s_id[tid] = 1.0f / (sqrtf(s + 1e-7f) + 1e-7f);
    } else if (tid < DTILE + TQ) {
        int q = tid - DTILE;
        float s = pnq[0][q] + pnq[1][q];
        s_iq[q] = 1.0f / (sqrtf(s + 1e-7f) + 1e-7f);
    }
    for (int i = tid; i < TQ * NFEAT; i += THREADS) s_hist[i] = 0u;
    __syncthreads();

    // ---- epilogue: sim -> bins (FULLY unrolled: acc must stay in registers)
    {
        const float id0 = s_id[myd];
        const float id1 = s_id[myd + 1];
        const bool  v0  = (toks[myd] != 0);
        const bool  v1  = (toks[myd + 1] != 0);
#pragma unroll
        for (int qi = 0; qi < 8; ++qi) {
            const int q = q0 + qi;
            const float iq = s_iq[q];
            if (v0) bin_one(acc[qi][0] * iq * id0, s_hist, q);
            if (v1) bin_one(acc[qi][1] * iq * id1, s_hist, q);
        }
    }
    __syncthreads();
    for (int i = tid; i < TQ * NFEAT; i += THREADS) {
        unsigned v = s_hist[i];
        if (v) atomicAdd(&ghist[b * TQ * NFEAT + i], v);
    }
}

// ---------------- finish: log + MLP + gate softmax ----------------
__global__ void k_finish(const unsigned* __restrict__ ghist,
                         const int* __restrict__ qsent, const float* __restrict__ idf,
                         const float* __restrict__ w1, const float* __restrict__ b1,
                         const float* __restrict__ w2, const float* __restrict__ b2,
                         const float* __restrict__ gw, const float* __restrict__ ow,
                         const float* __restrict__ ob, float* __restrict__ out) {
    int b = blockIdx.x;
    int lane = threadIdx.x;   // 64 threads, lanes 0..31 active
    float ffw = 0.f;
    float logit = -3.0e38f;
    if (lane < TQ) {
        const unsigned* h = ghist + (b * TQ + lane) * NFEAT;
        float f[NFEAT];
        for (int k = 0; k < NFEAT; ++k) f[k] = logf((float)h[k] + 1.0f);
        float s2 = b2[0];
        for (int n = 0; n < 5; ++n) {
            float s = b1[n];
            for (int k = 0; k < NFEAT; ++k) s = fmaf(f[k], w1[k * 5 + n], s);
            s2 = fmaf(tanhf(s), w2[n], s2);
        }
        ffw = tanhf(s2);
        int qt = qsent[b * TQ + lane];
        logit = idf[b * TQ + lane] * gw[0] + (qt == 0 ? -1e7f : 0.f);
    }
    float m = logit;
#pragma unroll
    for (int t = 1; t < 64; t <<= 1) m = fmaxf(m, __shfl_xor(m, t, 64));
    float e = expf(logit - m);            // inactive lanes -> exp(-inf) = 0
    float se = e, sw = e * ffw;
#pragma unroll
    for (int t = 1; t < 64; t <<= 1) {
        se += __shfl_xor(se, t, 64);
        sw += __shfl_xor(sw, t, 64);
    }
    if (lane == 0) out[b] = (sw / se) * ow[0] + ob[0];
}

extern "C" void kernel_launch(void* const* d_in, const int* in_sizes, int n_in,
                              void* d_out, int out_size, void* d_ws, size_t ws_size,
                              hipStream_t stream) {
    const int*   sent  = (const int*)d_in[0];
    const int*   qsent = (const int*)d_in[1];
    const float* idf   = (const float*)d_in[2];
    const float* emb   = (const float*)d_in[3];
    const float* w1    = (const float*)d_in[4];
    const float* b1    = (const float*)d_in[5];
    const float* w2    = (const float*)d_in[6];
    const float* b2    = (const float*)d_in[7];
    const float* gw    = (const float*)d_in[8];
    const float* ow    = (const float*)d_in[9];
    const float* ob    = (const float*)d_in[10];
    float* out = (float*)d_out;

    unsigned* ghist = (unsigned*)d_ws;                 // 64*32*30 u32 = 240 KB

    hipMemsetAsync(ghist, 0, (size_t)B_ * TQ * NFEAT * 4, stream);
    k_main<<<B_ * NCHUNK, THREADS, 0, stream>>>(sent, qsent, emb, ghist);
    k_finish<<<B_, 64, 0, stream>>>(ghist, qsent, idf, w1, b1, w2, b2, gw, ow, ob, out);
}